// Round 11
// baseline (28.841 us; speedup 1.0000x reference)
//
#include <hip/hip_runtime.h>
#include <math.h>

#define NPAR 130048
#define EPSF 1e-5f
#define NTASK 159
#define MAGIC 0x13572468u
#define FLAGS_OFF 17000    // float offset in ws; uint32 flags[NTASK]

typedef _Float16 hfp;
typedef _Float16 h2x __attribute__((ext_vector_type(2)));
typedef _Float16 h4x __attribute__((ext_vector_type(4)));
typedef float    f4x __attribute__((ext_vector_type(4)));

// ---- strides ----
#define BSTR  164      // beta row stride (f32)
#define VSTR2 172      // vposT row stride (halves)
#define ATSTR 172      // att row stride (halves)
#define WOSTR 76       // Wo / L1 / O / H1 row stride (halves)
#define L2STRH 108     // L2 / R row stride (halves)

// ---- ws layout (float offsets) ----
#define OFF_VPOST 0        // f16 [64][172]
#define OFF_WO    5504     // f16 [64][76]
#define OFF_L1    7936     // f16 [96][76]
#define OFF_L2    11584    // f16 [64][108]
#define OFF_BETA  15040    // f32 [4][164]
#define OFF_SM    15696    // f32 smalls
#define SM_CT   0
#define SM_BO   64
#define SM_B1   128
#define SM_B2   224
#define SM_LN1W 288
#define SM_LN1B 352
#define SM_LN2W 416
#define SM_LN2B 480
#define SM_ALPH 544
#define SM_GAM  548
#define SM_BOCT 576        // bo + ct precombined

// ---- per-block LDS layout (float offsets) ----
#define L_W    0           // f32 [16][L] packed (max 2304)
#define L_WB   2304        // f32 [16]
#define L_ATT  2320        // f16 [64][172] = 5504 floats
#define L_INVS 7824        // f32 [64]
#define L_O    7888        // f16 [16][76] = 608
#define L_H1   8496        // f16 [16][76] = 608
#define L_R    9104        // f16 [16][108] = 864
#define L_PRE  9968        // f32 [16][68] = 1088
#define LDS_FLOATS 11072   // 44,288 B

template<int C>
__device__ __forceinline__ float dppf(float x) {
    return __int_as_float(__builtin_amdgcn_update_dpp(0, __float_as_int(x), C, 0xf, 0xf, false));
}
__device__ __forceinline__ float rowsum16(float x) {
    x += dppf<0x128>(x); x += dppf<0x124>(x); x += dppf<0x122>(x); x += dppf<0x121>(x);
    return x;
}
__device__ __forceinline__ unsigned packh2(float a, float b) {
    union { h2x h; unsigned u; } cv;
    cv.h.x = (hfp)a; cv.h.y = (hfp)b;
    return cv.u;
}

// ===================== producer tasks (64 lanes = wave 0 of blocks 0..158) =====================
__device__ __forceinline__ void pre_task(int j, int o,
    const float* pe, const float* ct, const float* W, const float* bq,
    const float* Wo, const float* bo, const float* L1w, const float* b1,
    const float* L2w, const float* b2,
    const float* ln1w, const float* ln1b, const float* ln2w, const float* ln2b,
    float* ws)
{
    hfp* wsh = (hfp*)ws;
    if (j < 145) {
        const float4* wq4 = (const float4*)(W + o*64);
        const float4* wk4 = (const float4*)(W + (64 + o)*64);
        const float4* wv4 = (const float4*)(W + (128 + o)*64);
        const float4* p4  = (const float4*)(pe + j*64);
        float sk = bq[64 + o], sv = bq[128 + o], sq = bq[o];
        #pragma unroll
        for (int e = 0; e < 16; ++e) {
            float4 k4 = wk4[e], v4 = wv4[e], q4 = wq4[e], pp = p4[e];
            float4 cc = ((const float4*)ct)[e];
            sk += k4.x*pp.x + k4.y*pp.y + k4.z*pp.z + k4.w*pp.w;
            sv += v4.x*pp.x + v4.y*pp.y + v4.z*pp.z + v4.w*pp.w;
            sq += q4.x*cc.x + q4.y*cc.y + q4.z*cc.z + q4.w*cc.w;
        }
        wsh[o*VSTR2 + j] = (hfp)sv;
        float r = sq * sk;
        #pragma unroll
        for (int off = 1; off < 16; off <<= 1) r += __shfl_xor(r, off);
        if ((o & 15) == 0) ws[OFF_BETA + (o >> 4)*BSTR + j] = r;
    } else if (j == 145) {
        const float4* wq4 = (const float4*)(W + o*64);
        const float4* wk4 = (const float4*)(W + (64 + o)*64);
        const float4* wv4 = (const float4*)(W + (128 + o)*64);
        float sq = bq[o], sk = bq[64 + o], sv = bq[128 + o], suk = 0.f, suv = 0.f;
        #pragma unroll
        for (int e = 0; e < 16; ++e) {
            float4 k4 = wk4[e], v4 = wv4[e], q4 = wq4[e];
            float4 cc = ((const float4*)ct)[e];
            sq += q4.x*cc.x + q4.y*cc.y + q4.z*cc.z + q4.w*cc.w;
            sk += k4.x*cc.x + k4.y*cc.y + k4.z*cc.z + k4.w*cc.w;
            sv += v4.x*cc.x + v4.y*cc.y + v4.z*cc.z + v4.w*cc.w;
            suk += k4.x + k4.y + k4.z + k4.w;
            suv += v4.x + v4.y + v4.z + v4.w;
        }
        wsh[o*VSTR2 + 156] = (hfp)sv;     // vcls
        wsh[o*VSTR2 + 157] = (hfp)suv;    // uv
        #pragma unroll
        for (int c = 145; c < 156; ++c) wsh[o*VSTR2 + c] = (hfp)0.f;
        wsh[o*VSTR2 + 158] = (hfp)0.f;
        wsh[o*VSTR2 + 159] = (hfp)0.f;
        float a = sq * suk, g = sq * sk;
        #pragma unroll
        for (int off = 1; off < 16; off <<= 1) {
            a += __shfl_xor(a, off);
            g += __shfl_xor(g, off);
        }
        if ((o & 15) == 0) {
            ws[OFF_SM + SM_ALPH + (o >> 4)] = a;
            ws[OFF_SM + SM_GAM  + (o >> 4)] = g;
        }
    } else if (j == 146) {
        ws[OFF_SM + SM_CT   + o] = ct[o];
        ws[OFF_SM + SM_BO   + o] = bo[o];
        ws[OFF_SM + SM_BOCT + o] = bo[o] + ct[o];
        ws[OFF_SM + SM_B2   + o] = b2[o];
        ws[OFF_SM + SM_LN1W + o] = ln1w[o];
        ws[OFF_SM + SM_LN1B + o] = ln1b[o];
        ws[OFF_SM + SM_LN2W + o] = ln2w[o];
        ws[OFF_SM + SM_LN2B + o] = ln2b[o];
        ws[OFF_SM + SM_B1   + o] = b1[o];
        if (o < 32) ws[OFF_SM + SM_B1 + 64 + o] = b1[64 + o];
    } else if (j < 151) {            // Wo quarters: 4096 -> 4 x 1024
        const int q = j - 147;
        #pragma unroll
        for (int i = 0; i < 16; ++i) {
            int idx = q*1024 + i*64 + o;
            wsh[OFF_WO*2 + (idx >> 6)*WOSTR + (idx & 63)] = (hfp)Wo[idx];
        }
    } else if (j < 155) {            // L1 quarters: 6144 -> 4 x 1536
        const int q = j - 151;
        #pragma unroll
        for (int i = 0; i < 24; ++i) {
            int idx = q*1536 + i*64 + o;
            wsh[OFF_L1*2 + (idx >> 6)*WOSTR + (idx & 63)] = (hfp)L1w[idx];
        }
    } else {                         // L2 quarters: 6144 -> 4 x 1536
        const int q = j - 155;
        #pragma unroll
        for (int i = 0; i < 24; ++i) {
            int idx = q*1536 + i*64 + o;
            int r = idx / 96, c = idx - r*96;
            wsh[OFF_L2*2 + r*L2STRH + c] = (hfp)L2w[idx];
        }
    }
}

// ===================== consumer: 4 waves, 16 seqs, two-pass softmax + MFMA =====================
template<int L>
__device__ __forceinline__ void consumer(const float* ws, float* lds, float* out,
                                         int b, int k0, int kgo)
{
    const int tid  = threadIdx.x;
    const int wave = tid >> 6;
    const int lane = tid & 63;
    const int e16  = lane & 15;
    const int g4   = (lane >> 4) * 4;
    const int c0   = e16 * 4;
    const hfp* wsh  = (const hfp*)ws;
    const hfp* ldsh = (const hfp*)lds;

    // ---- register prefetch of all weight fragments / scalars (overlaps softmax) ----
    h4x vpf[10];
    #pragma unroll
    for (int kt = 0; kt < 10; ++kt)
        vpf[kt] = *(const h4x*)(wsh + (16*wave + e16)*VSTR2 + kt*16 + g4);
    h4x wof[4];
    #pragma unroll
    for (int kt = 0; kt < 4; ++kt)
        wof[kt] = *(const h4x*)(wsh + OFF_WO*2 + (16*wave + e16)*WOSTR + kt*16 + g4);
    h4x l1f[2][4];
    float b1v[2];
    #pragma unroll
    for (int u = 0; u < 2; ++u) {
        const int tt = wave + 4*u;
        if (tt < 6) {
            #pragma unroll
            for (int kt = 0; kt < 4; ++kt)
                l1f[u][kt] = *(const h4x*)(wsh + OFF_L1*2 + (16*tt + e16)*WOSTR + kt*16 + g4);
            b1v[u] = ws[OFF_SM + SM_B1 + 16*tt + e16];
        }
    }
    h4x l2f[6];
    #pragma unroll
    for (int kt = 0; kt < 6; ++kt)
        l2f[kt] = *(const h4x*)(wsh + OFF_L2*2 + (16*wave + e16)*L2STRH + kt*16 + g4);
    const int nw = 16*wave + e16;
    const float boct = ws[OFF_SM + SM_BOCT + nw];
    const float b2v  = ws[OFF_SM + SM_B2   + nw];
    const f4x ln1w4 = *(const f4x*)(ws + OFF_SM + SM_LN1W + c0);
    const f4x ln1b4 = *(const f4x*)(ws + OFF_SM + SM_LN1B + c0);
    const f4x ln2w4 = *(const f4x*)(ws + OFF_SM + SM_LN2W + c0);
    const f4x ln2b4 = *(const f4x*)(ws + OFF_SM + SM_LN2B + c0);

    // ---- softmax: row r = m*4+h = tid>>2, segment q = tid&3; two-pass true max ----
    {
        const int r = tid >> 2;
        const int m = r >> 2, h = r & 3, q = tid & 3;
        const float alpha = ws[OFF_SM + SM_ALPH + h];
        const float gam   = ws[OFF_SM + SM_GAM  + h];
        const float* wr = lds + L_W + m*L;
        const float* br = ws + OFF_BETA + h*BSTR;
        const float wbias = lds[L_WB + m];

        // pass 1: true row max
        float mx = 0.25f * gam;
        #pragma unroll
        for (int t = 0; t < 10; ++t) {
            const int j0 = 16*t + 4*q;
            if (j0 + 3 < L) {
                f4x wv = *(const f4x*)(wr + j0);
                f4x bv = *(const f4x*)(br + j0);
                mx = fmaxf(mx, fmaf(alpha, wv.x, bv.x)*0.25f);
                mx = fmaxf(mx, fmaf(alpha, wv.y, bv.y)*0.25f);
                mx = fmaxf(mx, fmaf(alpha, wv.z, bv.z)*0.25f);
                mx = fmaxf(mx, fmaf(alpha, wv.w, bv.w)*0.25f);
            } else if (j0 <= L) {
                #pragma unroll
                for (int ee = 0; ee < 4; ++ee) {
                    int j = j0 + ee;
                    if (j <= L) {
                        float w = (j < L) ? wr[j] : wbias;
                        mx = fmaxf(mx, fmaf(alpha, w, br[j])*0.25f);
                    }
                }
            }
        }
        mx = fmaxf(mx, __shfl_xor(mx, 1));
        mx = fmaxf(mx, __shfl_xor(mx, 2));
        const float M = mx;

        // pass 2: exp + store f16 + S/WS
        unsigned* arow32 = (unsigned*)(lds + L_ATT) + r*(ATSTR/2);
        float S = 0.f, WS = 0.f;
        #pragma unroll
        for (int t = 0; t < 10; ++t) {
            const int j0 = 16*t + 4*q;
            if (j0 + 3 < L) {
                f4x wv = *(const f4x*)(wr + j0);
                f4x bv = *(const f4x*)(br + j0);
                float p0 = __expf(fmaf(alpha, wv.x, bv.x)*0.25f - M);
                float p1 = __expf(fmaf(alpha, wv.y, bv.y)*0.25f - M);
                float p2 = __expf(fmaf(alpha, wv.z, bv.z)*0.25f - M);
                float p3 = __expf(fmaf(alpha, wv.w, bv.w)*0.25f - M);
                S  += (p0 + p1) + (p2 + p3);
                WS += (p0*wv.x + p1*wv.y) + (p2*wv.z + p3*wv.w);
                uint2 u; u.x = packh2(p0, p1); u.y = packh2(p2, p3);
                *(uint2*)(arow32 + (j0 >> 1)) = u;
            } else if (j0 <= L) {
                float pv4[4] = {0.f, 0.f, 0.f, 0.f};
                #pragma unroll
                for (int ee = 0; ee < 4; ++ee) {
                    int j = j0 + ee;
                    if (j <= L) {
                        float w = (j < L) ? wr[j] : wbias;
                        float p = __expf(fmaf(alpha, w, br[j])*0.25f - M);
                        S += p; WS += p*w; pv4[ee] = p;
                    }
                }
                uint2 u; u.x = packh2(pv4[0], pv4[1]); u.y = packh2(pv4[2], pv4[3]);
                *(uint2*)(arow32 + (j0 >> 1)) = u;
            } else if (j0 != 156) {
                uint2 z; z.x = 0u; z.y = 0u;
                *(uint2*)(arow32 + (j0 >> 1)) = z;
            }
        }
        S  += __shfl_xor(S, 1);  S  += __shfl_xor(S, 2);
        WS += __shfl_xor(WS, 1); WS += __shfl_xor(WS, 2);
        const float pc = __expf(0.25f*gam - M);     // CLS
        S += pc;
        if (q == 0) {
            lds[L_INVS + r] = 1.f / S;
            arow32[78] = packh2(pc, WS);            // cols 156 (a0), 157 (wsum)
            arow32[79] = 0u;
        }
    }
    __syncthreads();

    // ---- V-step (wave = head) ----
    {
        const hfp* atth = ldsh + L_ATT*2;
        const int hh = wave;
        f4x vacc = (f4x){0.f,0.f,0.f,0.f};
        #pragma unroll
        for (int kt = 0; kt < 10; ++kt) {
            h4x a = *(const h4x*)(atth + (e16*4 + hh)*ATSTR + kt*16 + g4);
            vacc = __builtin_amdgcn_mfma_f32_16x16x16f16(a, vpf[kt], vacc, 0, 0, 0);
        }
        hfp* Oh = (hfp*)(lds + L_O);
        #pragma unroll
        for (int rr = 0; rr < 4; ++rr) {
            float sc = lds[L_INVS + (g4 + rr)*4 + hh];
            Oh[(g4 + rr)*WOSTR + 16*hh + e16] = (hfp)(vacc[rr] * sc);
        }
    }
    __syncthreads();

    // ---- out-proj (wave = 16-col tile) ----
    {
        const hfp* Oh = ldsh + L_O*2;
        f4x pacc = (f4x){0.f,0.f,0.f,0.f};
        #pragma unroll
        for (int kt = 0; kt < 4; ++kt) {
            h4x a = *(const h4x*)(Oh + e16*WOSTR + kt*16 + g4);
            pacc = __builtin_amdgcn_mfma_f32_16x16x16f16(a, wof[kt], pacc, 0, 0, 0);
        }
        #pragma unroll
        for (int rr = 0; rr < 4; ++rr)
            lds[L_PRE + (g4 + rr)*68 + nw] = pacc[rr] + boct;
    }
    __syncthreads();

    // ---- LN1 (wave owns 4 rows) ----
    {
        const int m = wave*4 + (lane >> 4);
        f4x pv = *(const f4x*)(lds + L_PRE + m*68 + c0);
        float s = (pv.x + pv.y) + (pv.z + pv.w);
        float mu = rowsum16(s) * (1.f/64.f);
        f4x d; d.x = pv.x-mu; d.y = pv.y-mu; d.z = pv.z-mu; d.w = pv.w-mu;
        float v = (d.x*d.x + d.y*d.y) + (d.z*d.z + d.w*d.w);
        float rs = rsqrtf(rowsum16(v)*(1.f/64.f) + EPSF);
        h4x hv;
        hv.x = (hfp)(d.x*rs*ln1w4.x + ln1b4.x);
        hv.y = (hfp)(d.y*rs*ln1w4.y + ln1b4.y);
        hv.z = (hfp)(d.z*rs*ln1w4.z + ln1b4.z);
        hv.w = (hfp)(d.w*rs*ln1w4.w + ln1b4.w);
        *(h4x*)((hfp*)(lds + L_H1) + m*WOSTR + c0) = hv;
    }
    __syncthreads();

    // ---- FF1 + relu ----
    {
        const hfp* H1h = ldsh + L_H1*2;
        h4x af[4];
        #pragma unroll
        for (int kt = 0; kt < 4; ++kt) af[kt] = *(const h4x*)(H1h + e16*WOSTR + kt*16 + g4);
        hfp* Rh = (hfp*)(lds + L_R);
        #pragma unroll
        for (int u = 0; u < 2; ++u) {
            const int tt = wave + 4*u;
            if (tt < 6) {
                f4x racc = (f4x){0.f,0.f,0.f,0.f};
                #pragma unroll
                for (int kt = 0; kt < 4; ++kt)
                    racc = __builtin_amdgcn_mfma_f32_16x16x16f16(af[kt], l1f[u][kt], racc, 0, 0, 0);
                const int n = 16*tt + e16;
                #pragma unroll
                for (int rr = 0; rr < 4; ++rr)
                    Rh[(g4 + rr)*L2STRH + n] = (hfp)fmaxf(racc[rr] + b1v[u], 0.f);
            }
        }
    }
    __syncthreads();

    // ---- FF2 ----
    {
        const hfp* Rh2 = ldsh + L_R*2;
        f4x yacc = (f4x){0.f,0.f,0.f,0.f};
        #pragma unroll
        for (int kt = 0; kt < 6; ++kt) {
            h4x a = *(const h4x*)(Rh2 + e16*L2STRH + kt*16 + g4);
            yacc = __builtin_amdgcn_mfma_f32_16x16x16f16(a, l2f[kt], yacc, 0, 0, 0);
        }
        #pragma unroll
        for (int rr = 0; rr < 4; ++rr)
            lds[L_PRE + (g4 + rr)*68 + nw] = yacc[rr] + b2v;
    }
    __syncthreads();

    // ---- LN2 + residual(h1) + store ----
    {
        const int m = wave*4 + (lane >> 4);
        f4x pv = *(const f4x*)(lds + L_PRE + m*68 + c0);
        h4x h1p = *(const h4x*)((const hfp*)(lds + L_H1) + m*WOSTR + c0);
        f4x tot;
        tot.x = pv.x + (float)h1p.x;
        tot.y = pv.y + (float)h1p.y;
        tot.z = pv.z + (float)h1p.z;
        tot.w = pv.w + (float)h1p.w;
        float s = (tot.x + tot.y) + (tot.z + tot.w);
        float mu = rowsum16(s) * (1.f/64.f);
        f4x d; d.x = tot.x-mu; d.y = tot.y-mu; d.z = tot.z-mu; d.w = tot.w-mu;
        float v = (d.x*d.x + d.y*d.y) + (d.z*d.z + d.w*d.w);
        float rs = rsqrtf(rowsum16(v)*(1.f/64.f) + EPSF);
        f4x y;
        y.x = d.x*rs*ln2w4.x + ln2b4.x;
        y.y = d.y*rs*ln2w4.y + ln2b4.y;
        y.z = d.z*rs*ln2w4.z + ln2b4.z;
        y.w = d.w*rs*ln2w4.w + ln2b4.w;
        float* ob = out + ((size_t)b*1024 + kgo + k0 + m)*128;
        *(f4x*)(ob + c0)      = y;
        *(f4x*)(ob + 64 + c0) = y;   // tile (1,1,2)
    }
}

// ===================== fused kernel: producers (wave 0 of blocks 0..158) + consumers =====================
__global__ __launch_bounds__(256, 1) void k_all(
    const float* __restrict__ x,
    const float* pe, const float* ct, const float* W, const float* bq,
    const float* Wo, const float* bo, const float* L1w, const float* b1,
    const float* L2w, const float* b2,
    const float* ln1w, const float* ln1b, const float* ln2w, const float* ln2b,
    float* ws, float* __restrict__ out)
{
    __shared__ __align__(16) float lds[LDS_FLOATS];
    const int tid  = threadIdx.x;
    const int wave = tid >> 6;
    const int lane = tid & 63;
    const int w    = blockIdx.x;
    unsigned* flags = (unsigned*)(ws + FLAGS_OFF);

    // group decode
    int b, k0, start, kno, kgo; bool big;
    if (w < 64)       { b = w >> 4;            k0 = (w & 15)*16; start = 0;     kno = 256; kgo = 0;   big = false; }
    else if (w < 128) { int g = w - 64;  b = g >> 4; k0 = (g & 15)*16; start = 18688; kno = 256; kgo = 256; big = true; }
    else              { int g = w - 128; b = g >> 5; k0 = (g & 31)*16; start = 55808; kno = 512; kgo = 512; big = true; }
    const int L = big ? 144 : 72;
    const bool prod = (w < NTASK);

    // ---- phase 0: producer (wave 0) ∥ x-staging (other waves / all waves) ----
    if (prod && wave == 0) {
        pre_task(w, lane, pe, ct, W, bq, Wo, bo, L1w, b1, L2w, b2,
                 ln1w, ln1b, ln2w, ln2b, ws);
        __threadfence();
        if (lane == 0)
            __hip_atomic_store(&flags[w], MAGIC, __ATOMIC_RELEASE, __HIP_MEMORY_SCOPE_AGENT);
    } else {
        const int st = prod ? tid - 64 : tid;
        const int sn = prod ? 192 : 256;
        const f4x* src = (const f4x*)(x + (size_t)b*NPAR + start + (size_t)k0*L);
        f4x* dst = (f4x*)(lds + L_W);
        for (int i4 = st; i4 < 4*L; i4 += sn) dst[i4] = src[i4];
        if (st < 16) lds[L_WB + st] = x[(size_t)b*NPAR + start + (size_t)kno*L + k0 + st];
    }

    // ---- phase 0b: acquire-spin on all producer flags ----
    if (tid < NTASK) {
        unsigned v;
        do {
            v = __hip_atomic_load(&flags[tid], __ATOMIC_ACQUIRE, __HIP_MEMORY_SCOPE_AGENT);
            if (v != MAGIC) __builtin_amdgcn_s_sleep(2);
        } while (v != MAGIC);
    }
    __syncthreads();

    if (big) consumer<144>(ws, lds, out, b, k0, kgo);
    else     consumer<72> (ws, lds, out, b, k0, kgo);
}

extern "C" void kernel_launch(void* const* d_in, const int* in_sizes, int n_in,
                              void* d_out, int out_size, void* d_ws, size_t ws_size,
                              hipStream_t stream) {
    const float* x    = (const float*)d_in[0];
    const float* pe   = (const float*)d_in[1];
    const float* ct   = (const float*)d_in[2];
    const float* Wq   = (const float*)d_in[3];
    const float* bq   = (const float*)d_in[4];
    const float* Wo   = (const float*)d_in[5];
    const float* bo   = (const float*)d_in[6];
    const float* L1w  = (const float*)d_in[7];
    const float* b1   = (const float*)d_in[8];
    const float* L2w  = (const float*)d_in[9];
    const float* b2   = (const float*)d_in[10];
    const float* ln1w = (const float*)d_in[11];
    const float* ln1b = (const float*)d_in[12];
    const float* ln2w = (const float*)d_in[13];
    const float* ln2b = (const float*)d_in[14];
    float* out = (float*)d_out;
    float* ws  = (float*)d_ws;

    k_all<<<256, 256, 0, stream>>>(x, pe, ct, Wq, bq, Wo, bo, L1w, b1, L2w, b2,
                                   ln1w, ln1b, ln2w, ln2b, ws, out);
}

// Round 12
// 20.236 us; speedup vs baseline: 1.4253x; 1.4253x over previous
//
#include <hip/hip_runtime.h>
#include <math.h>

#define NPAR 130048
#define EPSF 1e-5f

typedef _Float16 hfp;
typedef _Float16 h2x __attribute__((ext_vector_type(2)));
typedef _Float16 h4x __attribute__((ext_vector_type(4)));
typedef float    f4x __attribute__((ext_vector_type(4)));

// ---- strides ----
#define BSTR  164      // beta row stride (f32)
#define VSTR2 172      // vposT row stride (halves)
#define ATSTR 172      // att row stride (halves)
#define WOSTR 76       // Wo / L1 / O / H1 row stride (halves)
#define L2STRH 108     // L2 / R row stride (halves)

// ---- ws layout (float offsets) — produced by k_pre, read directly (L2) by k_main ----
#define OFF_VPOST 0        // f16 [64][172]
#define OFF_WO    5504     // f16 [64][76]
#define OFF_L1    7936     // f16 [96][76]
#define OFF_L2    11584    // f16 [64][108]
#define OFF_BETA  15040    // f32 [4][164]
#define OFF_SM    15696    // f32 smalls
#define SM_CT   0
#define SM_BO   64
#define SM_B1   128
#define SM_B2   224
#define SM_LN1W 288
#define SM_LN1B 352
#define SM_LN2W 416
#define SM_LN2B 480
#define SM_ALPH 544
#define SM_GAM  548
#define SM_BOCT 576        // bo + ct precombined

// ---- per-block LDS (float offsets), 8-seq group ----
#define L_W    0           // f32 [8][L] packed (max 1152)
#define L_WB   1152        // f32 [8]
#define L_ATT  1168        // f16 [32][172] = 2752 floats
#define L_INVS 3920        // f32 [32]
#define L_O    3952        // f16 [8][76] = 304
#define L_H1   4256        // f16 [8][76] = 304
#define L_R    4560        // f16 [8][108] = 432
#define L_PRE  4992        // f32 [8][68] = 544
#define LDS_FLOATS 5536    // 22,144 B

template<int C>
__device__ __forceinline__ float dppf(float x) {
    return __int_as_float(__builtin_amdgcn_update_dpp(0, __float_as_int(x), C, 0xf, 0xf, false));
}
__device__ __forceinline__ float rowsum16(float x) {
    x += dppf<0x128>(x); x += dppf<0x124>(x); x += dppf<0x122>(x); x += dppf<0x121>(x);
    return x;
}
__device__ __forceinline__ unsigned packh2(float a, float b) {
    union { h2x h; unsigned u; } cv;
    cv.h.x = (hfp)a; cv.h.y = (hfp)b;
    return cv.u;
}

// ===================== k_pre: identical to R9 =====================
__global__ __launch_bounds__(64) void k_pre(const float* __restrict__ pe,
                                            const float* __restrict__ ct,
                                            const float* __restrict__ W,
                                            const float* __restrict__ bq,
                                            const float* __restrict__ Wo,
                                            const float* __restrict__ bo,
                                            const float* __restrict__ L1w,
                                            const float* __restrict__ b1,
                                            const float* __restrict__ L2w,
                                            const float* __restrict__ b2,
                                            const float* __restrict__ ln1w,
                                            const float* __restrict__ ln1b,
                                            const float* __restrict__ ln2w,
                                            const float* __restrict__ ln2b,
                                            float* __restrict__ ws)
{
    const int j = blockIdx.x;
    const int o = threadIdx.x;
    hfp* wsh = (hfp*)ws;

    if (j < 145) {
        const float4* wq4 = (const float4*)(W + o*64);
        const float4* wk4 = (const float4*)(W + (64 + o)*64);
        const float4* wv4 = (const float4*)(W + (128 + o)*64);
        const float4* p4  = (const float4*)(pe + j*64);
        float sk = bq[64 + o], sv = bq[128 + o], sq = bq[o];
        #pragma unroll
        for (int e = 0; e < 16; ++e) {
            float4 k4 = wk4[e], v4 = wv4[e], q4 = wq4[e], pp = p4[e];
            float4 cc = ((const float4*)ct)[e];
            sk += k4.x*pp.x + k4.y*pp.y + k4.z*pp.z + k4.w*pp.w;
            sv += v4.x*pp.x + v4.y*pp.y + v4.z*pp.z + v4.w*pp.w;
            sq += q4.x*cc.x + q4.y*cc.y + q4.z*cc.z + q4.w*cc.w;
        }
        wsh[o*VSTR2 + j] = (hfp)sv;
        float r = sq * sk;
        #pragma unroll
        for (int off = 1; off < 16; off <<= 1) r += __shfl_xor(r, off);
        if ((o & 15) == 0) ws[OFF_BETA + (o >> 4)*BSTR + j] = r;
    } else if (j == 145) {
        const float4* wq4 = (const float4*)(W + o*64);
        const float4* wk4 = (const float4*)(W + (64 + o)*64);
        const float4* wv4 = (const float4*)(W + (128 + o)*64);
        float sq = bq[o], sk = bq[64 + o], sv = bq[128 + o], suk = 0.f, suv = 0.f;
        #pragma unroll
        for (int e = 0; e < 16; ++e) {
            float4 k4 = wk4[e], v4 = wv4[e], q4 = wq4[e];
            float4 cc = ((const float4*)ct)[e];
            sq += q4.x*cc.x + q4.y*cc.y + q4.z*cc.z + q4.w*cc.w;
            sk += k4.x*cc.x + k4.y*cc.y + k4.z*cc.z + k4.w*cc.w;
            sv += v4.x*cc.x + v4.y*cc.y + v4.z*cc.z + v4.w*cc.w;
            suk += k4.x + k4.y + k4.z + k4.w;
            suv += v4.x + v4.y + v4.z + v4.w;
        }
        wsh[o*VSTR2 + 156] = (hfp)sv;     // vcls
        wsh[o*VSTR2 + 157] = (hfp)suv;    // uv
        #pragma unroll
        for (int c = 145; c < 156; ++c) wsh[o*VSTR2 + c] = (hfp)0.f;
        wsh[o*VSTR2 + 158] = (hfp)0.f;
        wsh[o*VSTR2 + 159] = (hfp)0.f;
        float a = sq * suk, g = sq * sk;
        #pragma unroll
        for (int off = 1; off < 16; off <<= 1) {
            a += __shfl_xor(a, off);
            g += __shfl_xor(g, off);
        }
        if ((o & 15) == 0) {
            ws[OFF_SM + SM_ALPH + (o >> 4)] = a;
            ws[OFF_SM + SM_GAM  + (o >> 4)] = g;
        }
    } else if (j == 146) {
        ws[OFF_SM + SM_CT   + o] = ct[o];
        ws[OFF_SM + SM_BO   + o] = bo[o];
        ws[OFF_SM + SM_BOCT + o] = bo[o] + ct[o];
        ws[OFF_SM + SM_B2   + o] = b2[o];
        ws[OFF_SM + SM_LN1W + o] = ln1w[o];
        ws[OFF_SM + SM_LN1B + o] = ln1b[o];
        ws[OFF_SM + SM_LN2W + o] = ln2w[o];
        ws[OFF_SM + SM_LN2B + o] = ln2b[o];
        ws[OFF_SM + SM_B1   + o] = b1[o];
        if (o < 32) ws[OFF_SM + SM_B1 + 64 + o] = b1[64 + o];
    } else if (j == 147) {
        for (int idx = o; idx < 4096; idx += 64)
            wsh[OFF_WO*2 + (idx >> 6)*WOSTR + (idx & 63)] = (hfp)Wo[idx];
    } else if (j == 148) {
        for (int idx = o; idx < 6144; idx += 64)
            wsh[OFF_L1*2 + (idx >> 6)*WOSTR + (idx & 63)] = (hfp)L1w[idx];
    } else {
        for (int idx = o; idx < 6144; idx += 64) {
            int r = idx / 96, c = idx - r*96;
            wsh[OFF_L2*2 + r*L2STRH + c] = (hfp)L2w[idx];
        }
    }
}

// ===================== k_main: 512 blocks x 4 waves, 8 seqs per block =====================
template<int L>
__device__ __forceinline__ void run_group(const float* __restrict__ x,
                                          const float* __restrict__ ws,
                                          float* __restrict__ lds,
                                          float* __restrict__ out,
                                          int b, int k0, int start, int kno, int kgo)
{
    const int tid  = threadIdx.x;
    const int wave = tid >> 6;
    const int lane = tid & 63;
    const int e16  = lane & 15;
    const int e8   = e16 & 7;
    const int g4   = (lane >> 4) * 4;
    const int c0   = e16 * 4;
    const hfp* wsh  = (const hfp*)ws;
    const hfp* ldsh = (const hfp*)lds;

    // ---- stage x (8 seqs, contiguous) ----
    {
        const f4x* src = (const f4x*)(x + (size_t)b*NPAR + start + (size_t)k0*L);
        f4x* dst = (f4x*)(lds + L_W);
        #pragma unroll
        for (int c = 0; c < (2*L + 255)/256; ++c) {
            int i4 = c*256 + tid;
            if (i4 < 2*L) dst[i4] = src[i4];
        }
        if (tid < 8) lds[L_WB + tid] = x[(size_t)b*NPAR + start + (size_t)kno*L + k0 + tid];
    }

    // ---- register prefetch of weight fragments / scalars (overlaps softmax) ----
    h4x vpf[10];
    #pragma unroll
    for (int kt = 0; kt < 10; ++kt)
        vpf[kt] = *(const h4x*)(wsh + (16*wave + e16)*VSTR2 + kt*16 + g4);
    h4x wof[4];
    #pragma unroll
    for (int kt = 0; kt < 4; ++kt)
        wof[kt] = *(const h4x*)(wsh + OFF_WO*2 + (16*wave + e16)*WOSTR + kt*16 + g4);
    h4x l1f[2][4];
    float b1v[2];
    #pragma unroll
    for (int u = 0; u < 2; ++u) {
        const int tt = wave + 4*u;
        if (tt < 6) {
            #pragma unroll
            for (int kt = 0; kt < 4; ++kt)
                l1f[u][kt] = *(const h4x*)(wsh + OFF_L1*2 + (16*tt + e16)*WOSTR + kt*16 + g4);
            b1v[u] = ws[OFF_SM + SM_B1 + 16*tt + e16];
        }
    }
    h4x l2f[6];
    #pragma unroll
    for (int kt = 0; kt < 6; ++kt)
        l2f[kt] = *(const h4x*)(wsh + OFF_L2*2 + (16*wave + e16)*L2STRH + kt*16 + g4);
    const int nw = 16*wave + e16;
    const float boct = ws[OFF_SM + SM_BOCT + nw];
    const float b2v  = ws[OFF_SM + SM_B2   + nw];
    const f4x ln1w4 = *(const f4x*)(ws + OFF_SM + SM_LN1W + c0);
    const f4x ln1b4 = *(const f4x*)(ws + OFF_SM + SM_LN1B + c0);
    const f4x ln2w4 = *(const f4x*)(ws + OFF_SM + SM_LN2W + c0);
    const f4x ln2b4 = *(const f4x*)(ws + OFF_SM + SM_LN2B + c0);
    __syncthreads();

    // ---- softmax: 32 rows (m*4+h = tid>>3) x 8 segments (q = tid&7); two-pass true max ----
    {
        const int r = tid >> 3;
        const int m = r >> 2, h = r & 3, q = tid & 7;
        const float alpha = ws[OFF_SM + SM_ALPH + h];
        const float gam   = ws[OFF_SM + SM_GAM  + h];
        const float* wr = lds + L_W + m*L;
        const float* br = ws + OFF_BETA + h*BSTR;
        const float wbias = lds[L_WB + m];

        // pass 1: true row max
        float mx = 0.25f * gam;
        #pragma unroll
        for (int t = 0; t < 5; ++t) {
            const int j0 = 32*t + 4*q;
            if (j0 + 3 < L) {
                f4x wv = *(const f4x*)(wr + j0);
                f4x bv = *(const f4x*)(br + j0);
                mx = fmaxf(mx, fmaf(alpha, wv.x, bv.x)*0.25f);
                mx = fmaxf(mx, fmaf(alpha, wv.y, bv.y)*0.25f);
                mx = fmaxf(mx, fmaf(alpha, wv.z, bv.z)*0.25f);
                mx = fmaxf(mx, fmaf(alpha, wv.w, bv.w)*0.25f);
            } else if (j0 <= L) {
                #pragma unroll
                for (int ee = 0; ee < 4; ++ee) {
                    int j = j0 + ee;
                    if (j <= L) {
                        float w = (j < L) ? wr[j] : wbias;
                        mx = fmaxf(mx, fmaf(alpha, w, br[j])*0.25f);
                    }
                }
            }
        }
        mx = fmaxf(mx, __shfl_xor(mx, 1));
        mx = fmaxf(mx, __shfl_xor(mx, 2));
        mx = fmaxf(mx, __shfl_xor(mx, 4));
        const float M = mx;

        // pass 2: exp + f16 store + S/WS
        unsigned* arow32 = (unsigned*)(lds + L_ATT) + r*(ATSTR/2);
        float S = 0.f, WS = 0.f;
        #pragma unroll
        for (int t = 0; t < 5; ++t) {
            const int j0 = 32*t + 4*q;
            if (j0 + 3 < L) {
                f4x wv = *(const f4x*)(wr + j0);
                f4x bv = *(const f4x*)(br + j0);
                float p0 = __expf(fmaf(alpha, wv.x, bv.x)*0.25f - M);
                float p1 = __expf(fmaf(alpha, wv.y, bv.y)*0.25f - M);
                float p2 = __expf(fmaf(alpha, wv.z, bv.z)*0.25f - M);
                float p3 = __expf(fmaf(alpha, wv.w, bv.w)*0.25f - M);
                S  += (p0 + p1) + (p2 + p3);
                WS += (p0*wv.x + p1*wv.y) + (p2*wv.z + p3*wv.w);
                uint2 u; u.x = packh2(p0, p1); u.y = packh2(p2, p3);
                *(uint2*)(arow32 + (j0 >> 1)) = u;
            } else if (j0 <= L) {
                float pv4[4] = {0.f, 0.f, 0.f, 0.f};
                #pragma unroll
                for (int ee = 0; ee < 4; ++ee) {
                    int j = j0 + ee;
                    if (j <= L) {
                        float w = (j < L) ? wr[j] : wbias;
                        float p = __expf(fmaf(alpha, w, br[j])*0.25f - M);
                        S += p; WS += p*w; pv4[ee] = p;
                    }
                }
                uint2 u; u.x = packh2(pv4[0], pv4[1]); u.y = packh2(pv4[2], pv4[3]);
                *(uint2*)(arow32 + (j0 >> 1)) = u;
            } else if (j0 != 156) {
                uint2 z; z.x = 0u; z.y = 0u;
                *(uint2*)(arow32 + (j0 >> 1)) = z;
            }
        }
        S  += __shfl_xor(S, 1);  S  += __shfl_xor(S, 2);  S  += __shfl_xor(S, 4);
        WS += __shfl_xor(WS, 1); WS += __shfl_xor(WS, 2); WS += __shfl_xor(WS, 4);
        const float pc = __expf(0.25f*gam - M);     // CLS
        S += pc;
        if (q == 0) {
            lds[L_INVS + r] = 1.f / S;
            arow32[78] = packh2(pc, WS);            // cols 156 (a0), 157 (wsum)
            arow32[79] = 0u;
        }
    }
    __syncthreads();

    // ---- V-step (wave = head; M=8, rows duplicated via e8) ----
    {
        const hfp* atth = ldsh + L_ATT*2;
        const int hh = wave;
        f4x vacc = (f4x){0.f,0.f,0.f,0.f};
        #pragma unroll
        for (int kt = 0; kt < 10; ++kt) {
            h4x a = *(const h4x*)(atth + (e8*4 + hh)*ATSTR + kt*16 + g4);
            vacc = __builtin_amdgcn_mfma_f32_16x16x16f16(a, vpf[kt], vacc, 0, 0, 0);
        }
        hfp* Oh = (hfp*)(lds + L_O);
        #pragma unroll
        for (int rr = 0; rr < 4; ++rr) {
            const int mrow = g4 + rr;
            if (mrow < 8)
                Oh[mrow*WOSTR + 16*hh + e16] = (hfp)(vacc[rr] * lds[L_INVS + mrow*4 + hh]);
        }
    }
    __syncthreads();

    // ---- out-proj (wave = 16-col tile) ----
    {
        const hfp* Oh = ldsh + L_O*2;
        f4x pacc = (f4x){0.f,0.f,0.f,0.f};
        #pragma unroll
        for (int kt = 0; kt < 4; ++kt) {
            h4x a = *(const h4x*)(Oh + e8*WOSTR + kt*16 + g4);
            pacc = __builtin_amdgcn_mfma_f32_16x16x16f16(a, wof[kt], pacc, 0, 0, 0);
        }
        #pragma unroll
        for (int rr = 0; rr < 4; ++rr) {
            const int mrow = g4 + rr;
            if (mrow < 8) lds[L_PRE + mrow*68 + nw] = pacc[rr] + boct;
        }
    }
    __syncthreads();

    // ---- LN1 (waves 0-1: 8 rows) ----
    {
        const int m = wave*4 + (lane >> 4);
        if (m < 8) {
            f4x pv = *(const f4x*)(lds + L_PRE + m*68 + c0);
            float s = (pv.x + pv.y) + (pv.z + pv.w);
            float mu = rowsum16(s) * (1.f/64.f);
            f4x d; d.x = pv.x-mu; d.y = pv.y-mu; d.z = pv.z-mu; d.w = pv.w-mu;
            float v = (d.x*d.x + d.y*d.y) + (d.z*d.z + d.w*d.w);
            float rs = rsqrtf(rowsum16(v)*(1.f/64.f) + EPSF);
            h4x hv;
            hv.x = (hfp)(d.x*rs*ln1w4.x + ln1b4.x);
            hv.y = (hfp)(d.y*rs*ln1w4.y + ln1b4.y);
            hv.z = (hfp)(d.z*rs*ln1w4.z + ln1b4.z);
            hv.w = (hfp)(d.w*rs*ln1w4.w + ln1b4.w);
            *(h4x*)((hfp*)(lds + L_H1) + m*WOSTR + c0) = hv;
        }
    }
    __syncthreads();

    // ---- FF1 + relu ----
    {
        const hfp* H1h = ldsh + L_H1*2;
        h4x af[4];
        #pragma unroll
        for (int kt = 0; kt < 4; ++kt) af[kt] = *(const h4x*)(H1h + e8*WOSTR + kt*16 + g4);
        hfp* Rh = (hfp*)(lds + L_R);
        #pragma unroll
        for (int u = 0; u < 2; ++u) {
            const int tt = wave + 4*u;
            if (tt < 6) {
                f4x racc = (f4x){0.f,0.f,0.f,0.f};
                #pragma unroll
                for (int kt = 0; kt < 4; ++kt)
                    racc = __builtin_amdgcn_mfma_f32_16x16x16f16(af[kt], l1f[u][kt], racc, 0, 0, 0);
                const int n = 16*tt + e16;
                #pragma unroll
                for (int rr = 0; rr < 4; ++rr) {
                    const int mrow = g4 + rr;
                    if (mrow < 8) Rh[mrow*L2STRH + n] = (hfp)fmaxf(racc[rr] + b1v[u], 0.f);
                }
            }
        }
    }
    __syncthreads();

    // ---- FF2 ----
    {
        const hfp* Rh2 = ldsh + L_R*2;
        f4x yacc = (f4x){0.f,0.f,0.f,0.f};
        #pragma unroll
        for (int kt = 0; kt < 6; ++kt) {
            h4x a = *(const h4x*)(Rh2 + e8*L2STRH + kt*16 + g4);
            yacc = __builtin_amdgcn_mfma_f32_16x16x16f16(a, l2f[kt], yacc, 0, 0, 0);
        }
        #pragma unroll
        for (int rr = 0; rr < 4; ++rr) {
            const int mrow = g4 + rr;
            if (mrow < 8) lds[L_PRE + mrow*68 + nw] = yacc[rr] + b2v;
        }
    }
    __syncthreads();

    // ---- LN2 + residual(h1) + store (waves 0-1) ----
    {
        const int m = wave*4 + (lane >> 4);
        if (m < 8) {
            f4x pv = *(const f4x*)(lds + L_PRE + m*68 + c0);
            h4x h1p = *(const h4x*)((const hfp*)(lds + L_H1) + m*WOSTR + c0);
            f4x tot;
            tot.x = pv.x + (float)h1p.x;
            tot.y = pv.y + (float)h1p.y;
            tot.z = pv.z + (float)h1p.z;
            tot.w = pv.w + (float)h1p.w;
            float s = (tot.x + tot.y) + (tot.z + tot.w);
            float mu = rowsum16(s) * (1.f/64.f);
            f4x d; d.x = tot.x-mu; d.y = tot.y-mu; d.z = tot.z-mu; d.w = tot.w-mu;
            float v = (d.x*d.x + d.y*d.y) + (d.z*d.z + d.w*d.w);
            float rs = rsqrtf(rowsum16(v)*(1.f/64.f) + EPSF);
            f4x y;
            y.x = d.x*rs*ln2w4.x + ln2b4.x;
            y.y = d.y*rs*ln2w4.y + ln2b4.y;
            y.z = d.z*rs*ln2w4.z + ln2b4.z;
            y.w = d.w*rs*ln2w4.w + ln2b4.w;
            float* ob = out + ((size_t)b*1024 + kgo + k0 + m)*128;
            *(f4x*)(ob + c0)      = y;
            *(f4x*)(ob + 64 + c0) = y;   // tile (1,1,2)
        }
    }
}

__global__ __launch_bounds__(256, 2) void k_main(const float* __restrict__ x,
                                                 const float* __restrict__ ws,
                                                 float* __restrict__ out)
{
    __shared__ __align__(16) float lds[LDS_FLOATS];
    const int w = blockIdx.x;
    if (w < 128) {
        run_group<72>(x, ws, lds, out, w >> 5, (w & 31)*8, 0, 256, 0);
    } else if (w < 256) {
        const int g = w - 128;
        run_group<144>(x, ws, lds, out, g >> 5, (g & 31)*8, 18688, 256, 256);
    } else {
        const int g = w - 256;
        run_group<144>(x, ws, lds, out, g >> 6, (g & 63)*8, 55808, 512, 512);
    }
}

extern "C" void kernel_launch(void* const* d_in, const int* in_sizes, int n_in,
                              void* d_out, int out_size, void* d_ws, size_t ws_size,
                              hipStream_t stream) {
    const float* x    = (const float*)d_in[0];
    const float* pe   = (const float*)d_in[1];
    const float* ct   = (const float*)d_in[2];
    const float* Wq   = (const float*)d_in[3];
    const float* bq   = (const float*)d_in[4];
    const float* Wo   = (const float*)d_in[5];
    const float* bo   = (const float*)d_in[6];
    const float* L1w  = (const float*)d_in[7];
    const float* b1   = (const float*)d_in[8];
    const float* L2w  = (const float*)d_in[9];
    const float* b2   = (const float*)d_in[10];
    const float* ln1w = (const float*)d_in[11];
    const float* ln1b = (const float*)d_in[12];
    const float* ln2w = (const float*)d_in[13];
    const float* ln2b = (const float*)d_in[14];
    float* out = (float*)d_out;
    float* ws  = (float*)d_ws;

    k_pre <<<150, 64, 0, stream>>>(pe, ct, Wq, bq, Wo, bo, L1w, b1, L2w, b2,
                                   ln1w, ln1b, ln2w, ln2b, ws);
    k_main<<<512, 256, 0, stream>>>(x, ws, out);
}

// Round 13
// 19.258 us; speedup vs baseline: 1.4976x; 1.0508x over previous
//
#include <hip/hip_runtime.h>
#include <math.h>

#define NPAR 130048
#define EPSF 1e-5f

typedef _Float16 hfp;
typedef _Float16 h2x __attribute__((ext_vector_type(2)));
typedef _Float16 h4x __attribute__((ext_vector_type(4)));
typedef float    f4x __attribute__((ext_vector_type(4)));

// ---- strides ----
#define BSTR  164      // beta row stride (f32)
#define VSTR2 172      // vposT row stride (halves)
#define ATSTR 172      // att row stride (halves)
#define WOSTR 76       // O / H1 row stride (halves)
#define L2STRH 108     // R row stride (halves)

// ---- per-block LDS (float offsets) ----
#define L_W    0           // f32 [16][L] packed (max 2304)
#define L_WB   2304        // f32 [16]
#define L_ATT  2320        // f16 [64][172] = 5504 floats
#define L_INVS 7824        // f32 [64]
#define L_O    7888        // f16 [16][76] = 608
#define L_H1   8496        // f16 [16][76] = 608
#define L_R    9104        // f16 [16][108] = 864
#define L_PRE  9968        // f32 [16][68] = 1088
#define L_VPOS 11056       // f16 [64][172] = 5504
#define L_BETA 16560       // f32 [4][164] = 656
#define L_QK   17216       // f16 [4][64] = 128
#define L_SM   17344       // smalls: 332
#define SM_Q0   0
#define SM_KCLS 64
#define SM_VCLS 128
#define SM_UK   192
#define SM_UV   256
#define SM_ALPH 320
#define SM_GAM  324
#define SM_QB   328
#define LDS_FLOATS 17676   // 70,704 B

template<int C>
__device__ __forceinline__ float dppf(float x) {
    return __int_as_float(__builtin_amdgcn_update_dpp(0, __float_as_int(x), C, 0xf, 0xf, false));
}
__device__ __forceinline__ float rowsum16(float x) {
    x += dppf<0x128>(x); x += dppf<0x124>(x); x += dppf<0x122>(x); x += dppf<0x121>(x);
    return x;
}
__device__ __forceinline__ unsigned packh2(float a, float b) {
    union { h2x h; unsigned u; } cv;
    cv.h.x = (hfp)a; cv.h.y = (hfp)b;
    return cv.u;
}
__device__ __forceinline__ h4x cvt4(f4x v) {
    h4x r; r.x = (hfp)v.x; r.y = (hfp)v.y; r.z = (hfp)v.z; r.w = (hfp)v.w; return r;
}

// ===================== single fused kernel: each block self-contained =====================
template<int L>
__device__ __forceinline__ void run_group(
    const float* __restrict__ x,  const float* __restrict__ pe,
    const float* __restrict__ ct, const float* __restrict__ W,
    const float* __restrict__ bq, const float* __restrict__ Wo,
    const float* __restrict__ bo, const float* __restrict__ L1w,
    const float* __restrict__ b1, const float* __restrict__ L2w,
    const float* __restrict__ b2,
    const float* __restrict__ ln1w, const float* __restrict__ ln1b,
    const float* __restrict__ ln2w, const float* __restrict__ ln2b,
    float* __restrict__ lds, float* __restrict__ out,
    int b, int k0, int start, int kno, int kgo)
{
    const int tid  = threadIdx.x;
    const int wave = tid >> 6;
    const int lane = tid & 63;
    const int e16  = lane & 15;
    const int g4   = (lane >> 4) * 4;
    const int c0   = e16 * 4;
    const hfp* ldsh = (const hfp*)lds;

    // ================= P0: x-stage + in_proj row dots + per-lane weight frag loads =================
    {
        const f4x* src = (const f4x*)(x + (size_t)b*NPAR + start + (size_t)k0*L);
        f4x* dst = (f4x*)(lds + L_W);
        #pragma unroll
        for (int c = 0; c < (4*L + 255)/256; ++c) {
            int i4 = c*256 + tid;
            if (i4 < 4*L) dst[i4] = src[i4];
        }
        if (tid < 16) lds[L_WB + tid] = x[(size_t)b*NPAR + start + (size_t)kno*L + k0 + tid];
    }
    if (tid < 192) {
        const f4x* wr4 = (const f4x*)(W + tid*64);
        const f4x* ct4 = (const f4x*)ct;
        float dotc = bq[tid], rsum = 0.f;
        #pragma unroll
        for (int e = 0; e < 16; ++e) {
            f4x wv = wr4[e], cc = ct4[e];
            dotc += (wv.x*cc.x + wv.y*cc.y) + (wv.z*cc.z + wv.w*cc.w);
            rsum += (wv.x + wv.y) + (wv.z + wv.w);
        }
        const int cls = tid >> 6, o = tid & 63;
        if (cls == 0)      lds[L_SM + SM_Q0 + o] = dotc;
        else if (cls == 1) { lds[L_SM + SM_KCLS + o] = dotc; lds[L_SM + SM_UK + o] = rsum; }
        else               { lds[L_SM + SM_VCLS + o] = dotc; lds[L_SM + SM_UV + o] = rsum; }
    }

    // per-lane weight fragments from global f32 (L2/L3-hot across blocks)
    h4x wof[4];
    #pragma unroll
    for (int kt = 0; kt < 4; ++kt)
        wof[kt] = cvt4(*(const f4x*)(Wo + (16*wave + e16)*64 + kt*16 + g4));
    h4x l1f[2][4];
    float b1v[2];
    #pragma unroll
    for (int u = 0; u < 2; ++u) {
        const int tt = wave + 4*u;
        if (tt < 6) {
            #pragma unroll
            for (int kt = 0; kt < 4; ++kt)
                l1f[u][kt] = cvt4(*(const f4x*)(L1w + (16*tt + e16)*64 + kt*16 + g4));
            b1v[u] = b1[16*tt + e16];
        }
    }
    h4x l2f[6];
    #pragma unroll
    for (int kt = 0; kt < 6; ++kt)
        l2f[kt] = cvt4(*(const f4x*)(L2w + (16*wave + e16)*96 + kt*16 + g4));
    const int nw = 16*wave + e16;
    const float boct = bo[nw] + ct[nw];
    const float b2v  = b2[nw];
    const f4x ln1w4 = *(const f4x*)(ln1w + c0);
    const f4x ln1b4 = *(const f4x*)(ln1b + c0);
    const f4x ln2w4 = *(const f4x*)(ln2w + c0);
    const f4x ln2b4 = *(const f4x*)(ln2b + c0);
    __syncthreads();

    // ================= P1: qk[4][64] (f16), alpha/gam/qb =================
    {
        const int h = wave, d = lane;
        float acc = 0.f;
        #pragma unroll
        for (int e = 0; e < 16; ++e)
            acc += lds[L_SM + SM_Q0 + h*16 + e] * W[(64 + h*16 + e)*64 + d];
        ((hfp*)(lds + L_QK))[h*64 + d] = (hfp)acc;
    }
    if (lane < 16) {
        const int h = wave, e = lane;
        const float q0e = lds[L_SM + SM_Q0 + h*16 + e];
        float pa = q0e * lds[L_SM + SM_UK + h*16 + e];
        float pg = q0e * lds[L_SM + SM_KCLS + h*16 + e];
        float pq = q0e * bq[64 + h*16 + e];
        pa = rowsum16(pa); pg = rowsum16(pg); pq = rowsum16(pq);
        if (e == 0) {
            lds[L_SM + SM_ALPH + h] = pa;
            lds[L_SM + SM_GAM  + h] = pg;
            lds[L_SM + SM_QB   + h] = pq;
        }
    }
    __syncthreads();

    // ================= P2: vposT = Wv@peT + bv, beta = qk@peT + qb (MFMA) =================
    {
        const int w = wave, r16 = lane & 15, kg = lane >> 4;   // kg in 0..3
        h4x av[4];
        #pragma unroll
        for (int kt = 0; kt < 4; ++kt)
            av[kt] = cvt4(*(const f4x*)(W + (128 + 16*w + r16)*64 + kt*16 + kg*4));
        h4x ab[4];
        #pragma unroll
        for (int kt = 0; kt < 4; ++kt) {
            if (r16 < 4) ab[kt] = *(const h4x*)((const hfp*)(lds + L_QK) + r16*64 + kt*16 + kg*4);
            else         { h4x z; z.x = (hfp)0.f; z.y = (hfp)0.f; z.z = (hfp)0.f; z.w = (hfp)0.f; ab[kt] = z; }
        }
        const f4x bv4 = *(const f4x*)(bq + 128 + 16*w + kg*4);
        hfp* vpos_h = (hfp*)(lds + L_VPOS);
        #pragma unroll
        for (int jt = 0; jt < 10; ++jt) {
            const int j = jt*16 + r16;
            h4x bf[4];
            #pragma unroll
            for (int kt = 0; kt < 4; ++kt) {
                if (j < 145) bf[kt] = cvt4(*(const f4x*)(pe + j*64 + kt*16 + kg*4));
                else { h4x z; z.x = (hfp)0.f; z.y = (hfp)0.f; z.z = (hfp)0.f; z.w = (hfp)0.f; bf[kt] = z; }
            }
            f4x acc = (f4x){0.f,0.f,0.f,0.f};
            #pragma unroll
            for (int kt = 0; kt < 4; ++kt)
                acc = __builtin_amdgcn_mfma_f32_16x16x16f16(av[kt], bf[kt], acc, 0, 0, 0);
            #pragma unroll
            for (int rr = 0; rr < 4; ++rr) {
                if (j < 145) vpos_h[(16*w + kg*4 + rr)*VSTR2 + j] = (hfp)(acc[rr] + bv4[rr]);
            }
            if ((jt & 3) == w) {      // this wave also does beta for jt
                f4x accb = (f4x){0.f,0.f,0.f,0.f};
                #pragma unroll
                for (int kt = 0; kt < 4; ++kt)
                    accb = __builtin_amdgcn_mfma_f32_16x16x16f16(ab[kt], bf[kt], accb, 0, 0, 0);
                if (lane < 16) {
                    const int jj = jt*16 + lane;
                    if (jj < 145) {
                        #pragma unroll
                        for (int rr = 0; rr < 4; ++rr)
                            lds[L_BETA + rr*BSTR + jj] = accb[rr] + lds[L_SM + SM_QB + rr];
                    }
                }
            }
        }
    }
    if (tid < 64) {   // vcls/uv columns + zero pads
        hfp* vpos_h = (hfp*)(lds + L_VPOS);
        const int d = tid;
        #pragma unroll
        for (int c = 145; c < 156; ++c) vpos_h[d*VSTR2 + c] = (hfp)0.f;
        vpos_h[d*VSTR2 + 156] = (hfp)lds[L_SM + SM_VCLS + d];
        vpos_h[d*VSTR2 + 157] = (hfp)lds[L_SM + SM_UV + d];
        vpos_h[d*VSTR2 + 158] = (hfp)0.f;
        vpos_h[d*VSTR2 + 159] = (hfp)0.f;
    }
    __syncthreads();

    // ================= P3: softmax (64 rows x 4 segments, two-pass true max) =================
    {
        const int r = tid >> 2;
        const int m = r >> 2, h = r & 3, q = tid & 3;
        const float alpha = lds[L_SM + SM_ALPH + h];
        const float gam   = lds[L_SM + SM_GAM  + h];
        const float* wr = lds + L_W + m*L;
        const float* br = lds + L_BETA + h*BSTR;
        const float wbias = lds[L_WB + m];

        float mx = 0.25f * gam;
        #pragma unroll
        for (int t = 0; t < 10; ++t) {
            const int j0 = 16*t + 4*q;
            if (j0 + 3 < L) {
                f4x wv = *(const f4x*)(wr + j0);
                f4x bv = *(const f4x*)(br + j0);
                mx = fmaxf(mx, fmaf(alpha, wv.x, bv.x)*0.25f);
                mx = fmaxf(mx, fmaf(alpha, wv.y, bv.y)*0.25f);
                mx = fmaxf(mx, fmaf(alpha, wv.z, bv.z)*0.25f);
                mx = fmaxf(mx, fmaf(alpha, wv.w, bv.w)*0.25f);
            } else if (j0 <= L) {
                #pragma unroll
                for (int ee = 0; ee < 4; ++ee) {
                    int j = j0 + ee;
                    if (j <= L) {
                        float w = (j < L) ? wr[j] : wbias;
                        mx = fmaxf(mx, fmaf(alpha, w, br[j])*0.25f);
                    }
                }
            }
        }
        mx = fmaxf(mx, __shfl_xor(mx, 1));
        mx = fmaxf(mx, __shfl_xor(mx, 2));
        const float M = mx;

        unsigned* arow32 = (unsigned*)(lds + L_ATT) + r*(ATSTR/2);
        float S = 0.f, WS = 0.f;
        #pragma unroll
        for (int t = 0; t < 10; ++t) {
            const int j0 = 16*t + 4*q;
            if (j0 + 3 < L) {
                f4x wv = *(const f4x*)(wr + j0);
                f4x bv = *(const f4x*)(br + j0);
                float p0 = __expf(fmaf(alpha, wv.x, bv.x)*0.25f - M);
                float p1 = __expf(fmaf(alpha, wv.y, bv.y)*0.25f - M);
                float p2 = __expf(fmaf(alpha, wv.z, bv.z)*0.25f - M);
                float p3 = __expf(fmaf(alpha, wv.w, bv.w)*0.25f - M);
                S  += (p0 + p1) + (p2 + p3);
                WS += (p0*wv.x + p1*wv.y) + (p2*wv.z + p3*wv.w);
                uint2 u; u.x = packh2(p0, p1); u.y = packh2(p2, p3);
                *(uint2*)(arow32 + (j0 >> 1)) = u;
            } else if (j0 <= L) {
                float pv4[4] = {0.f, 0.f, 0.f, 0.f};
                #pragma unroll
                for (int ee = 0; ee < 4; ++ee) {
                    int j = j0 + ee;
                    if (j <= L) {
                        float w = (j < L) ? wr[j] : wbias;
                        float p = __expf(fmaf(alpha, w, br[j])*0.25f - M);
                        S += p; WS += p*w; pv4[ee] = p;
                    }
                }
                uint2 u; u.x = packh2(pv4[0], pv4[1]); u.y = packh2(pv4[2], pv4[3]);
                *(uint2*)(arow32 + (j0 >> 1)) = u;
            } else if (j0 != 156) {
                uint2 z; z.x = 0u; z.y = 0u;
                *(uint2*)(arow32 + (j0 >> 1)) = z;
            }
        }
        S  += __shfl_xor(S, 1);  S  += __shfl_xor(S, 2);
        WS += __shfl_xor(WS, 1); WS += __shfl_xor(WS, 2);
        const float pc = __expf(0.25f*gam - M);
        S += pc;
        if (q == 0) {
            lds[L_INVS + r] = 1.f / S;
            arow32[78] = packh2(pc, WS);     // cols 156 (a0), 157 (wsum)
            arow32[79] = 0u;
        }
    }
    __syncthreads();

    // ================= P4: V-step (wave = head) =================
    {
        const hfp* atth = ldsh + L_ATT*2;
        const hfp* vpos_h = ldsh + L_VPOS*2;
        const int hh = wave;
        f4x vacc = (f4x){0.f,0.f,0.f,0.f};
        #pragma unroll
        for (int kt = 0; kt < 10; ++kt) {
            h4x a  = *(const h4x*)(atth + (e16*4 + hh)*ATSTR + kt*16 + g4);
            h4x bf = *(const h4x*)(vpos_h + (16*hh + e16)*VSTR2 + kt*16 + g4);
            vacc = __builtin_amdgcn_mfma_f32_16x16x16f16(a, bf, vacc, 0, 0, 0);
        }
        hfp* Oh = (hfp*)(lds + L_O);
        #pragma unroll
        for (int rr = 0; rr < 4; ++rr) {
            float sc = lds[L_INVS + (g4 + rr)*4 + hh];
            Oh[(g4 + rr)*WOSTR + 16*hh + e16] = (hfp)(vacc[rr] * sc);
        }
    }
    __syncthreads();

    // ================= P5: out-proj =================
    {
        const hfp* Oh = ldsh + L_O*2;
        f4x pacc = (f4x){0.f,0.f,0.f,0.f};
        #pragma unroll
        for (int kt = 0; kt < 4; ++kt) {
            h4x a = *(const h4x*)(Oh + e16*WOSTR + kt*16 + g4);
            pacc = __builtin_amdgcn_mfma_f32_16x16x16f16(a, wof[kt], pacc, 0, 0, 0);
        }
        #pragma unroll
        for (int rr = 0; rr < 4; ++rr)
            lds[L_PRE + (g4 + rr)*68 + nw] = pacc[rr] + boct;
    }
    __syncthreads();

    // ================= P6: LN1 =================
    {
        const int m = wave*4 + (lane >> 4);
        f4x pv = *(const f4x*)(lds + L_PRE + m*68 + c0);
        float s = (pv.x + pv.y) + (pv.z + pv.w);
        float mu = rowsum16(s) * (1.f/64.f);
        f4x d; d.x = pv.x-mu; d.y = pv.y-mu; d.z = pv.z-mu; d.w = pv.w-mu;
        float v = (d.x*d.x + d.y*d.y) + (d.z*d.z + d.w*d.w);
        float rs = rsqrtf(rowsum16(v)*(1.f/64.f) + EPSF);
        h4x hv;
        hv.x = (hfp)(d.x*rs*ln1w4.x + ln1b4.x);
        hv.y = (hfp)(d.y*rs*ln1w4.y + ln1b4.y);
        hv.z = (hfp)(d.z*rs*ln1w4.z + ln1b4.z);
        hv.w = (hfp)(d.w*rs*ln1w4.w + ln1b4.w);
        *(h4x*)((hfp*)(lds + L_H1) + m*WOSTR + c0) = hv;
    }
    __syncthreads();

    // ================= P7: FF1 + relu =================
    {
        const hfp* H1h = ldsh + L_H1*2;
        h4x af[4];
        #pragma unroll
        for (int kt = 0; kt < 4; ++kt) af[kt] = *(const h4x*)(H1h + e16*WOSTR + kt*16 + g4);
        hfp* Rh = (hfp*)(lds + L_R);
        #pragma unroll
        for (int u = 0; u < 2; ++u) {
            const int tt = wave + 4*u;
            if (tt < 6) {
                f4x racc = (f4x){0.f,0.f,0.f,0.f};
                #pragma unroll
                for (int kt = 0; kt < 4; ++kt)
                    racc = __builtin_amdgcn_mfma_f32_16x16x16f16(af[kt], l1f[u][kt], racc, 0, 0, 0);
                const int n = 16*tt + e16;
                #pragma unroll
                for (int rr = 0; rr < 4; ++rr)
                    Rh[(g4 + rr)*L2STRH + n] = (hfp)fmaxf(racc[rr] + b1v[u], 0.f);
            }
        }
    }
    __syncthreads();

    // ================= P8: FF2 =================
    {
        const hfp* Rh2 = ldsh + L_R*2;
        f4x yacc = (f4x){0.f,0.f,0.f,0.f};
        #pragma unroll
        for (int kt = 0; kt < 6; ++kt) {
            h4x a = *(const h4x*)(Rh2 + e16*L2STRH + kt*16 + g4);
            yacc = __builtin_amdgcn_mfma_f32_16x16x16f16(a, l2f[kt], yacc, 0, 0, 0);
        }
        #pragma unroll
        for (int rr = 0; rr < 4; ++rr)
            lds[L_PRE + (g4 + rr)*68 + nw] = yacc[rr] + b2v;
    }
    __syncthreads();

    // ================= P9: LN2 + residual + store =================
    {
        const int m = wave*4 + (lane >> 4);
        f4x pv = *(const f4x*)(lds + L_PRE + m*68 + c0);
        h4x h1p = *(const h4x*)((const hfp*)(lds + L_H1) + m*WOSTR + c0);
        f4x tot;
        tot.x = pv.x + (float)h1p.x;
        tot.y = pv.y + (float)h1p.y;
        tot.z = pv.z + (float)h1p.z;
        tot.w = pv.w + (float)h1p.w;
        float s = (tot.x + tot.y) + (tot.z + tot.w);
        float mu = rowsum16(s) * (1.f/64.f);
        f4x d; d.x = tot.x-mu; d.y = tot.y-mu; d.z = tot.z-mu; d.w = tot.w-mu;
        float v = (d.x*d.x + d.y*d.y) + (d.z*d.z + d.w*d.w);
        float rs = rsqrtf(rowsum16(v)*(1.f/64.f) + EPSF);
        f4x y;
        y.x = d.x*rs*ln2w4.x + ln2b4.x;
        y.y = d.y*rs*ln2w4.y + ln2b4.y;
        y.z = d.z*rs*ln2w4.z + ln2b4.z;
        y.w = d.w*rs*ln2w4.w + ln2b4.w;
        float* ob = out + ((size_t)b*1024 + kgo + k0 + m)*128;
        *(f4x*)(ob + c0)      = y;
        *(f4x*)(ob + 64 + c0) = y;   // tile (1,1,2)
    }
}

__global__ __launch_bounds__(256, 1) void k_all(
    const float* __restrict__ x,  const float* __restrict__ pe,
    const float* __restrict__ ct, const float* __restrict__ W,
    const float* __restrict__ bq, const float* __restrict__ Wo,
    const float* __restrict__ bo, const float* __restrict__ L1w,
    const float* __restrict__ b1, const float* __restrict__ L2w,
    const float* __restrict__ b2,
    const float* __restrict__ ln1w, const float* __restrict__ ln1b,
    const float* __restrict__ ln2w, const float* __restrict__ ln2b,
    float* __restrict__ out)
{
    __shared__ __align__(16) float lds[LDS_FLOATS];
    const int w = blockIdx.x;
    if (w < 64) {
        run_group<72>(x, pe, ct, W, bq, Wo, bo, L1w, b1, L2w, b2,
                      ln1w, ln1b, ln2w, ln2b, lds, out,
                      w >> 4, (w & 15)*16, 0, 256, 0);
    } else if (w < 128) {
        const int g = w - 64;
        run_group<144>(x, pe, ct, W, bq, Wo, bo, L1w, b1, L2w, b2,
                       ln1w, ln1b, ln2w, ln2b, lds, out,
                       g >> 4, (g & 15)*16, 18688, 256, 256);
    } else {
        const int g = w - 128;
        run_group<144>(x, pe, ct, W, bq, Wo, bo, L1w, b1, L2w, b2,
                       ln1w, ln1b, ln2w, ln2b, lds, out,
                       g >> 5, (g & 31)*16, 55808, 512, 512);
    }
}

extern "C" void kernel_launch(void* const* d_in, const int* in_sizes, int n_in,
                              void* d_out, int out_size, void* d_ws, size_t ws_size,
                              hipStream_t stream) {
    const float* x    = (const float*)d_in[0];
    const float* pe   = (const float*)d_in[1];
    const float* ct   = (const float*)d_in[2];
    const float* Wq   = (const float*)d_in[3];
    const float* bq   = (const float*)d_in[4];
    const float* Wo   = (const float*)d_in[5];
    const float* bo   = (const float*)d_in[6];
    const float* L1w  = (const float*)d_in[7];
    const float* b1   = (const float*)d_in[8];
    const float* L2w  = (const float*)d_in[9];
    const float* b2   = (const float*)d_in[10];
    const float* ln1w = (const float*)d_in[11];
    const float* ln1b = (const float*)d_in[12];
    const float* ln2w = (const float*)d_in[13];
    const float* ln2b = (const float*)d_in[14];
    float* out = (float*)d_out;

    k_all<<<256, 256, 0, stream>>>(x, pe, ct, Wq, bq, Wo, bo, L1w, b1, L2w, b2,
                                   ln1w, ln1b, ln2w, ln2b, out);
}